// Round 1
// baseline (278.297 us; speedup 1.0000x reference)
//
#include <hip/hip_runtime.h>

#define BB 16
#define CC 80
#define HH 128
#define WW 128
#define HWs 16384           // H*W
#define KK 100
#define CAPB 16384          // per-batch candidate capacity (8B each -> 2MB total)
#define NBINS1 256
#define NBINS2 4096

__device__ __forceinline__ float sigmoidf_(float x) {
    return 1.0f / (1.0f + expf(-x));
}

__global__ void zero_counts_kernel(int* counts) {
    if (threadIdx.x < BB) counts[threadIdx.x] = 0;
}

// One block per (b, c) plane. Stage sigmoid plane in LDS, NMS, per-plane
// top-100 cutoff via 256-bin histogram, emit survivors to per-batch list.
__global__ __launch_bounds__(256) void nms_kernel(const float* __restrict__ hm,
                                                  unsigned long long* __restrict__ cand,
                                                  int* __restrict__ counts) {
    __shared__ float sm[HWs];        // 64 KB: sigmoid of the plane
    __shared__ int hist[NBINS1];
    __shared__ int scan[NBINS1];
    __shared__ int s_cut;
    __shared__ int s_base;

    const int plane = blockIdx.x;    // b*CC + c
    const int b = plane / CC;
    const int c = plane - b * CC;
    const int t = threadIdx.x;
    const float* __restrict__ src = hm + (size_t)plane * HWs;

    hist[t] = 0;
    const float4* src4 = reinterpret_cast<const float4*>(src);
    for (int i = t; i < HWs / 4; i += 256) {
        float4 v = src4[i];
        int p = i << 2;
        sm[p + 0] = sigmoidf_(v.x);
        sm[p + 1] = sigmoidf_(v.y);
        sm[p + 2] = sigmoidf_(v.z);
        sm[p + 3] = sigmoidf_(v.w);
    }
    __syncthreads();

    // peak detection (s >= all 8 neighbors' sigmoid, SAME padding) + histogram
    unsigned long long m = 0ull;
    for (int k = 0; k < 64; ++k) {
        int p = (k << 8) + t;
        float s = sm[p];
        int y = p >> 7, x = p & 127;
        int ylo = (y > 0) ? y - 1 : y, yhi = (y < 127) ? y + 1 : y;
        int xlo = (x > 0) ? x - 1 : x, xhi = (x < 127) ? x + 1 : x;
        bool peak = true;
        for (int ny = ylo; ny <= yhi; ++ny)
            for (int nx = xlo; nx <= xhi; ++nx)
                peak = peak && (s >= sm[(ny << 7) + nx]);
        if (peak) {
            m |= (1ull << k);
            int bin = (int)(s * (float)NBINS1);
            bin = bin > NBINS1 - 1 ? NBINS1 - 1 : bin;
            atomicAdd(&hist[bin], 1);
        }
    }
    __syncthreads();

    // inclusive suffix sum over hist -> scan[t] = count of peaks in bins >= t
    scan[t] = hist[t];
    __syncthreads();
    for (int off = 1; off < NBINS1; off <<= 1) {
        int v = (t + off < NBINS1) ? scan[t + off] : 0;
        __syncthreads();
        scan[t] += v;
        __syncthreads();
    }
    if (t == 0) s_cut = 0;
    __syncthreads();
    int total = scan[0];
    if (total > KK) {
        int nxt = (t < NBINS1 - 1) ? scan[t + 1] : 0;
        if (scan[t] >= KK && nxt < KK) s_cut = t;   // exactly one thread
    }
    __syncthreads();
    const int cut = s_cut;

    // count my survivors
    int mycnt = 0;
    unsigned long long mm = m;
    while (mm) {
        int k = __ffsll(mm) - 1;
        mm &= mm - 1;
        float s = sm[(k << 8) + t];
        int bin = (int)(s * (float)NBINS1);
        bin = bin > NBINS1 - 1 ? NBINS1 - 1 : bin;
        if (bin >= cut) ++mycnt;
    }
    // block inclusive scan (ascending) for write offsets
    scan[t] = mycnt;
    __syncthreads();
    for (int off = 1; off < 256; off <<= 1) {
        int v = (t >= off) ? scan[t - off] : 0;
        __syncthreads();
        scan[t] += v;
        __syncthreads();
    }
    int excl = scan[t] - mycnt;
    int tot = scan[255];
    if (t == 0) s_base = atomicAdd(&counts[b], tot);
    __syncthreads();
    const int base = s_base;

    unsigned long long* __restrict__ cb = cand + (size_t)b * CAPB;
    int w = 0;
    mm = m;
    while (mm) {
        int k = __ffsll(mm) - 1;
        mm &= mm - 1;
        int p = (k << 8) + t;
        float s = sm[p];
        int bin = (int)(s * (float)NBINS1);
        bin = bin > NBINS1 - 1 ? NBINS1 - 1 : bin;
        if (bin >= cut) {
            int slot = base + excl + w;
            if (slot < CAPB) {
                unsigned idx = (unsigned)(c * HWs + p);
                cb[slot] = ((unsigned long long)__float_as_uint(s) << 32) | idx;
            }
            ++w;
        }
    }
}

// One block per batch: exact top-100 with lax.top_k tie semantics
// (descending score, ties -> lower flat index first), then gather + emit.
__global__ __launch_bounds__(256) void topk_kernel(const unsigned long long* __restrict__ cand,
                                                   const int* __restrict__ counts,
                                                   const float* __restrict__ bbox,
                                                   const float* __restrict__ offs,
                                                   const int* __restrict__ image_id,
                                                   float* __restrict__ out) {
    __shared__ int hist[NBINS2];               // 16 KB
    __shared__ int csum[256];
    __shared__ unsigned long long list[2048];  // 16 KB
    __shared__ int s_cut, s_nsel;

    const int b = blockIdx.x;
    const int t = threadIdx.x;
    int Nc = counts[b];
    if (Nc > CAPB) Nc = CAPB;
    const unsigned long long* __restrict__ cb = cand + (size_t)b * CAPB;

    for (int i = t; i < NBINS2; i += 256) hist[i] = 0;
    if (t == 0) { s_cut = 0; s_nsel = 0; }
    __syncthreads();

    for (int i = t; i < Nc; i += 256) {
        float s = __uint_as_float((unsigned)(cb[i] >> 32));
        int bin = (int)(s * (float)NBINS2);
        bin = bin > NBINS2 - 1 ? NBINS2 - 1 : bin;
        atomicAdd(&hist[bin], 1);
    }
    __syncthreads();

    // chunk sums: thread t owns bins [16t, 16t+16)
    int chunk = 0;
#pragma unroll
    for (int j = 0; j < 16; ++j) chunk += hist[t * 16 + j];
    csum[t] = chunk;
    __syncthreads();
    for (int off = 1; off < 256; off <<= 1) {
        int v = (t + off < 256) ? csum[t + off] : 0;
        __syncthreads();
        csum[t] += v;
        __syncthreads();
    }
    int totalc = csum[0];
    if (totalc > KK) {
        int running = (t < 255) ? csum[t + 1] : 0;
        if (csum[t] >= KK && running < KK) {
            for (int j = 15; j >= 0; --j) {        // largest bin with suffix >= KK
                running += hist[t * 16 + j];
                if (running >= KK) { s_cut = t * 16 + j; break; }
            }
        }
    }
    __syncthreads();
    const int cut = s_cut;

    // collect survivors; key = (score_bits << 32) | ~idx  -> desc sort gives
    // score desc, index asc on ties (== lax.top_k)
    for (int i = t; i < Nc; i += 256) {
        unsigned long long cv = cb[i];
        float s = __uint_as_float((unsigned)(cv >> 32));
        int bin = (int)(s * (float)NBINS2);
        bin = bin > NBINS2 - 1 ? NBINS2 - 1 : bin;
        if (bin >= cut) {
            int slot = atomicAdd(&s_nsel, 1);
            if (slot < 2048) list[slot] = cv ^ 0xFFFFFFFFull;
        }
    }
    __syncthreads();
    int nsel = s_nsel; if (nsel > 2048) nsel = 2048;

    int P = 128;
    while (P < nsel) P <<= 1;
    for (int i = nsel + t; i < P; i += 256) list[i] = 0ull;
    __syncthreads();

    // bitonic sort, descending
    for (int ksz = 2; ksz <= P; ksz <<= 1) {
        for (int j = ksz >> 1; j > 0; j >>= 1) {
            for (int i = t; i < P; i += 256) {
                int ixj = i ^ j;
                if (ixj > i) {
                    unsigned long long a = list[i], bb2 = list[ixj];
                    bool desc = ((i & ksz) == 0);
                    if (desc ? (a < bb2) : (a > bb2)) { list[i] = bb2; list[ixj] = a; }
                }
            }
            __syncthreads();
        }
    }

    if (t < KK) {
        float s = 0.0f; unsigned idx = 0;
        if (t < nsel) {
            unsigned long long cv = list[t] ^ 0xFFFFFFFFull;
            s = __uint_as_float((unsigned)(cv >> 32));
            idx = (unsigned)(cv & 0xFFFFFFFFu);
        }
        unsigned sp = idx & (HWs - 1);
        float cls = (float)(idx >> 14);
        float ys = (float)(sp >> 7);
        float xs = (float)(sp & 127);
        const float* __restrict__ ob  = offs + (size_t)b * 2 * HWs;
        const float* __restrict__ bbx = bbox + (size_t)b * 2 * HWs;
        float cx = xs + ob[sp];
        float cy = ys + ob[HWs + sp];
        float w = bbx[sp];
        float h = bbx[HWs + sp];
        float* row = out + ((size_t)b * KK + t) * 7;
        row[0] = (float)image_id[b];
        row[1] = (cx - w * 0.5f) * 4.0f;
        row[2] = (cy - h * 0.5f) * 4.0f;
        row[3] = (cx + w * 0.5f) * 4.0f;
        row[4] = (cy + h * 0.5f) * 4.0f;
        row[5] = s;
        row[6] = cls;
    }
}

extern "C" void kernel_launch(void* const* d_in, const int* in_sizes, int n_in,
                              void* d_out, int out_size, void* d_ws, size_t ws_size,
                              hipStream_t stream) {
    const float* hm      = (const float*)d_in[0];
    const float* bbox    = (const float*)d_in[1];
    const float* offset  = (const float*)d_in[2];
    const int*   img_id  = (const int*)d_in[3];
    float* out = (float*)d_out;

    int* counts = (int*)d_ws;
    unsigned long long* cand = (unsigned long long*)((char*)d_ws + 256);

    zero_counts_kernel<<<1, 64, 0, stream>>>(counts);
    nms_kernel<<<BB * CC, 256, 0, stream>>>(hm, cand, counts);
    topk_kernel<<<BB, 256, 0, stream>>>(cand, counts, bbox, offset, img_id, out);
}

// Round 2
// 95.109 us; speedup vs baseline: 2.9261x; 2.9261x over previous
//
#include <hip/hip_runtime.h>

#define BB 16
#define CC 80
#define HWs 16384           // H*W
#define KK 100
#define CAPB 16384          // per-batch candidate capacity (8B each -> 2MB total)
#define NB1 4096            // K1 per-plane histogram bins (ordered key >> 20)
#define NBINS2 4096         // K2 per-batch sigmoid-bits histogram bins
#define MAXC 3072           // per-plane LDS candidate capacity (~1820 expected peaks)

__device__ __forceinline__ unsigned okey(float f) {
    unsigned u = __float_as_uint(f);
    return (u & 0x80000000u) ? ~u : (u | 0x80000000u);
}
__device__ __forceinline__ float okey_inv(unsigned k) {
    unsigned u = (k & 0x80000000u) ? (k & 0x7FFFFFFFu) : ~k;
    return __uint_as_float(u);
}

__global__ void zero_counts_kernel(int* counts) {
    if (threadIdx.x < BB) counts[threadIdx.x] = 0;
}

// One block per (b,c) plane. Separable 3x3 max on raw logits, register
// stencil (no plane LDS). Per-plane top-100 cutoff via 4096-bin ordered-key
// histogram; emit survivors (sigmoid computed only here) to per-batch list.
__global__ __launch_bounds__(256) void nms_kernel(const float* __restrict__ hm,
                                                  unsigned long long* __restrict__ cand,
                                                  int* __restrict__ counts) {
    __shared__ int hist[NB1];              // 16 KB
    __shared__ unsigned ckey[MAXC];        // 12 KB
    __shared__ unsigned short cpos[MAXC];  // 6 KB
    __shared__ int red[256];
    __shared__ int s_ncand, s_cut, s_base;

    const int plane = blockIdx.x;          // b*CC + c
    const int b = plane / CC;
    const int c = plane - b * CC;
    const int t = threadIdx.x;
    const int sx = t & 31;                 // 4-wide column strip
    const int x0 = sx << 2;
    const int band = t >> 5;               // 8 bands x 16 rows
    const int ys = band << 4;
    const float* __restrict__ src = hm + (size_t)plane * HWs;

    for (int i = t; i < NB1; i += 256) hist[i] = 0;
    if (t == 0) s_ncand = 0;
    __syncthreads();

    // load row r (clamped): values v and horizontal max-of-3 h
    auto loadrow = [&](int r, float4& v, float4& h) {
        r = r < 0 ? 0 : (r > 127 ? 127 : r);
        v = *reinterpret_cast<const float4*>(src + (r << 7) + x0);
        float vm1 = __shfl_up(v.w, 1, 32);
        float vp4 = __shfl_down(v.x, 1, 32);
        if (sx == 0) vm1 = v.x;       // SAME padding (clamp)
        if (sx == 31) vp4 = v.w;
        h.x = fmaxf(fmaxf(vm1, v.x), v.y);
        h.y = fmaxf(fmaxf(v.x, v.y), v.z);
        h.z = fmaxf(fmaxf(v.y, v.z), v.w);
        h.w = fmaxf(fmaxf(v.z, v.w), vp4);
    };

    float4 v0, vn, hm1, h0, hp1;
    loadrow(ys - 1, vn, hm1);   // vn discarded
    loadrow(ys, v0, h0);
    for (int y = ys; y < ys + 16; ++y) {
        loadrow(y + 1, vn, hp1);
        float m[4], vv[4];
        m[0] = fmaxf(fmaxf(hm1.x, h0.x), hp1.x);
        m[1] = fmaxf(fmaxf(hm1.y, h0.y), hp1.y);
        m[2] = fmaxf(fmaxf(hm1.z, h0.z), hp1.z);
        m[3] = fmaxf(fmaxf(hm1.w, h0.w), hp1.w);
        vv[0] = v0.x; vv[1] = v0.y; vv[2] = v0.z; vv[3] = v0.w;
#pragma unroll
        for (int j = 0; j < 4; ++j) {
            if (vv[j] >= m[j]) {               // peak (== since vv <= m always)
                unsigned k = okey(vv[j]);
                atomicAdd(&hist[k >> 20], 1);
                int slot = atomicAdd(&s_ncand, 1);
                if (slot < MAXC) {
                    ckey[slot] = k;
                    cpos[slot] = (unsigned short)((y << 7) | (x0 + j));
                }
            }
        }
        hm1 = h0; h0 = hp1; v0 = vn;
    }
    __syncthreads();
    int ncand = s_ncand; if (ncand > MAXC) ncand = MAXC;

    // suffix scan: red[t] = # peaks in bins >= 16t
    int chunk = 0;
#pragma unroll
    for (int j = 0; j < 16; ++j) chunk += hist[(t << 4) + j];
    red[t] = chunk;
    __syncthreads();
    for (int off = 1; off < 256; off <<= 1) {
        int v = (t + off < 256) ? red[t + off] : 0;
        __syncthreads();
        red[t] += v;
        __syncthreads();
    }
    if (t == 0) s_cut = 0;
    __syncthreads();
    if (red[0] > KK) {
        int running = (t < 255) ? red[t + 1] : 0;
        if (red[t] >= KK && running < KK) {        // exactly one thread
            for (int j = 15; j >= 0; --j) {        // largest bin w/ suffix >= KK
                running += hist[(t << 4) + j];
                if (running >= KK) { s_cut = (t << 4) + j; break; }
            }
        }
    }
    __syncthreads();
    const unsigned cutkey = (unsigned)s_cut << 20;

    // count survivors, block scan, one global atomic per block
    int mycnt = 0;
    for (int i = t; i < ncand; i += 256) if (ckey[i] >= cutkey) ++mycnt;
    red[t] = mycnt;
    __syncthreads();
    for (int off = 1; off < 256; off <<= 1) {
        int v = (t >= off) ? red[t - off] : 0;
        __syncthreads();
        red[t] += v;
        __syncthreads();
    }
    int excl = red[t] - mycnt;
    if (t == 0) s_base = atomicAdd(&counts[b], red[255]);
    __syncthreads();
    const int base = s_base;

    unsigned long long* __restrict__ cb = cand + (size_t)b * CAPB;
    int w = excl;
    for (int i = t; i < ncand; i += 256) {
        unsigned k = ckey[i];
        if (k >= cutkey) {
            int slot = base + w; ++w;
            if (slot < CAPB) {
                float lv = okey_inv(k);                 // exact logit bits
                float s = 1.0f / (1.0f + expf(-lv));    // sigmoid only here
                unsigned idx = ((unsigned)c << 14) | (unsigned)cpos[i];
                cb[slot] = ((unsigned long long)__float_as_uint(s) << 32) | idx;
            }
        }
    }
}

// One block per batch: exact top-100 with lax.top_k tie semantics
// (descending score, ties -> lower flat index first), then gather + emit.
__global__ __launch_bounds__(256) void topk_kernel(const unsigned long long* __restrict__ cand,
                                                   const int* __restrict__ counts,
                                                   const float* __restrict__ bbox,
                                                   const float* __restrict__ offs,
                                                   const int* __restrict__ image_id,
                                                   float* __restrict__ out) {
    __shared__ int hist[NBINS2];               // 16 KB
    __shared__ int csum[256];
    __shared__ unsigned long long list[2048];  // 16 KB
    __shared__ int s_cut, s_nsel;

    const int b = blockIdx.x;
    const int t = threadIdx.x;
    int Nc = counts[b];
    if (Nc > CAPB) Nc = CAPB;
    const unsigned long long* __restrict__ cb = cand + (size_t)b * CAPB;

    for (int i = t; i < NBINS2; i += 256) hist[i] = 0;
    if (t == 0) { s_cut = 0; s_nsel = 0; }
    __syncthreads();

    for (int i = t; i < Nc; i += 256) {
        float s = __uint_as_float((unsigned)(cb[i] >> 32));
        int bin = (int)(s * (float)NBINS2);
        bin = bin > NBINS2 - 1 ? NBINS2 - 1 : bin;
        atomicAdd(&hist[bin], 1);
    }
    __syncthreads();

    int chunk = 0;
#pragma unroll
    for (int j = 0; j < 16; ++j) chunk += hist[t * 16 + j];
    csum[t] = chunk;
    __syncthreads();
    for (int off = 1; off < 256; off <<= 1) {
        int v = (t + off < 256) ? csum[t + off] : 0;
        __syncthreads();
        csum[t] += v;
        __syncthreads();
    }
    int totalc = csum[0];
    if (totalc > KK) {
        int running = (t < 255) ? csum[t + 1] : 0;
        if (csum[t] >= KK && running < KK) {
            for (int j = 15; j >= 0; --j) {
                running += hist[t * 16 + j];
                if (running >= KK) { s_cut = t * 16 + j; break; }
            }
        }
    }
    __syncthreads();
    const int cut = s_cut;

    // key = (score_bits << 32) | ~idx -> desc sort == (score desc, idx asc)
    for (int i = t; i < Nc; i += 256) {
        unsigned long long cv = cb[i];
        float s = __uint_as_float((unsigned)(cv >> 32));
        int bin = (int)(s * (float)NBINS2);
        bin = bin > NBINS2 - 1 ? NBINS2 - 1 : bin;
        if (bin >= cut) {
            int slot = atomicAdd(&s_nsel, 1);
            if (slot < 2048) list[slot] = cv ^ 0xFFFFFFFFull;
        }
    }
    __syncthreads();
    int nsel = s_nsel; if (nsel > 2048) nsel = 2048;

    int P = 128;
    while (P < nsel) P <<= 1;
    for (int i = nsel + t; i < P; i += 256) list[i] = 0ull;
    __syncthreads();

    for (int ksz = 2; ksz <= P; ksz <<= 1) {
        for (int j = ksz >> 1; j > 0; j >>= 1) {
            for (int i = t; i < P; i += 256) {
                int ixj = i ^ j;
                if (ixj > i) {
                    unsigned long long a = list[i], bb2 = list[ixj];
                    bool desc = ((i & ksz) == 0);
                    if (desc ? (a < bb2) : (a > bb2)) { list[i] = bb2; list[ixj] = a; }
                }
            }
            __syncthreads();
        }
    }

    if (t < KK) {
        float s = 0.0f; unsigned idx = 0;
        if (t < nsel) {
            unsigned long long cv = list[t] ^ 0xFFFFFFFFull;
            s = __uint_as_float((unsigned)(cv >> 32));
            idx = (unsigned)(cv & 0xFFFFFFFFu);
        }
        unsigned sp = idx & (HWs - 1);
        float cls = (float)(idx >> 14);
        float ys = (float)(sp >> 7);
        float xs = (float)(sp & 127);
        const float* __restrict__ ob  = offs + (size_t)b * 2 * HWs;
        const float* __restrict__ bbx = bbox + (size_t)b * 2 * HWs;
        float cx = xs + ob[sp];
        float cy = ys + ob[HWs + sp];
        float w = bbx[sp];
        float h = bbx[HWs + sp];
        float* row = out + ((size_t)b * KK + t) * 7;
        row[0] = (float)image_id[b];
        row[1] = (cx - w * 0.5f) * 4.0f;
        row[2] = (cy - h * 0.5f) * 4.0f;
        row[3] = (cx + w * 0.5f) * 4.0f;
        row[4] = (cy + h * 0.5f) * 4.0f;
        row[5] = s;
        row[6] = cls;
    }
}

extern "C" void kernel_launch(void* const* d_in, const int* in_sizes, int n_in,
                              void* d_out, int out_size, void* d_ws, size_t ws_size,
                              hipStream_t stream) {
    const float* hm      = (const float*)d_in[0];
    const float* bbox    = (const float*)d_in[1];
    const float* offset  = (const float*)d_in[2];
    const int*   img_id  = (const int*)d_in[3];
    float* out = (float*)d_out;

    int* counts = (int*)d_ws;
    unsigned long long* cand = (unsigned long long*)((char*)d_ws + 256);

    zero_counts_kernel<<<1, 64, 0, stream>>>(counts);
    nms_kernel<<<BB * CC, 256, 0, stream>>>(hm, cand, counts);
    topk_kernel<<<BB, 256, 0, stream>>>(cand, counts, bbox, offset, img_id, out);
}